// Round 1
// baseline (561.891 us; speedup 1.0000x reference)
//
#include <hip/hip_runtime.h>

#define FCH 192
#define NPOS 64
#define PX 200   // pitch (bf16 elems) for [64][192]-shaped buffers
#define PH 72    // pitch for sHT [192][64]
#define PP 72    // pitch for sP  [64][64]

typedef float f32x4 __attribute__((ext_vector_type(4)));
typedef float float4_t __attribute__((ext_vector_type(4)));
typedef __bf16 bf16x8 __attribute__((ext_vector_type(8)));
typedef unsigned short ushort8_t __attribute__((ext_vector_type(8)));
typedef unsigned short ushort4_t __attribute__((ext_vector_type(4)));

__device__ __forceinline__ unsigned short f2bf(float f) {
  unsigned u = __builtin_bit_cast(unsigned, f);
  u += 0x7fffu + ((u >> 16) & 1u);   // RNE (finite inputs only)
  return (unsigned short)(u >> 16);
}

__device__ __forceinline__ bf16x8 frag_ld(const unsigned short* p) {
  return __builtin_bit_cast(bf16x8, *(const ushort8_t*)p);
}

// ---- prep: WT[m][n][k] = W_m[k][n] as bf16, m in {f,g,h,o} ----
__global__ void prep_weights(const float* __restrict__ Wf, const float* __restrict__ Wg,
                             const float* __restrict__ Wh, const float* __restrict__ Wo,
                             unsigned short* __restrict__ wt) {
  int t = blockIdx.x * blockDim.x + threadIdx.x;   // 4*192*48 threads
  int n = t % 192;
  int kb = (t / 192) % 48;
  int m = t / (192 * 48);
  const float* W = (m == 0) ? Wf : (m == 1) ? Wg : (m == 2) ? Wh : Wo;
  ushort4_t v;
#pragma unroll
  for (int i = 0; i < 4; ++i) v[i] = f2bf(W[(kb * 4 + i) * 192 + n]);
  *(ushort4_t*)(wt + ((size_t)(m * 192 + n) * 192 + kb * 4)) = v;
}

__global__ __launch_bounds__(256) void spatial_attn(
    const float* __restrict__ x, const unsigned short* __restrict__ wt,
    const float* __restrict__ bfv, const float* __restrict__ bgv,
    const float* __restrict__ bhv, const float* __restrict__ bov,
    const float* __restrict__ gamma_p, float* __restrict__ out) {
  __shared__ unsigned short lds[56832];            // 113664 B
  unsigned short* sX  = lds;                       // [64][PX] bf16 x
  unsigned short* sF  = lds + 12800;               // [64][PX] Fx[n][f]
  unsigned short* sG  = lds + 25600;               // [64][PX] Gx[n][f]
  unsigned short* sHT = lds + 38400;               // [192][PH] Hx^T[f][n]
  unsigned short* sP  = lds + 52224;               // [64][PP] attn[n][m]
  unsigned short* sS  = lds;                       // alias sX: second[n][f]

  const int b    = blockIdx.x;
  const int tid  = threadIdx.x;
  const int lane = tid & 63;
  const int w    = tid >> 6;      // wave 0..3
  const int l15  = lane & 15;
  const int l4   = lane >> 4;     // 0..3

  const float* xb = x + (size_t)b * (NPOS * FCH);

  // ---- stage x_b -> LDS bf16 ----
#pragma unroll
  for (int r = 0; r < 12; ++r) {
    int i = tid + 256 * r;                 // float4 index, 3072 total
    float4_t v = *(const float4_t*)(xb + (size_t)i * 4);
    int row = (i * 4) / FCH, col = (i * 4) % FCH;
    ushort4_t u;
#pragma unroll
    for (int q = 0; q < 4; ++q) u[q] = f2bf(v[q]);
    *(ushort4_t*)(sX + row * PX + col) = u;
  }
  __syncthreads();

  const unsigned short* WfT = wt;
  const unsigned short* WgT = wt + 36864;
  const unsigned short* WhT = wt + 73728;
  const unsigned short* WoT = wt + 110592;

  // ---- conv f,g (transposed GEMM: D[f][n] = WT * X^T), store dst[n][f] ----
  auto conv_T = [&](const unsigned short* WT, const float* bias, unsigned short* dst) {
    f32x4 acc[3][4];
#pragma unroll
    for (int mt = 0; mt < 3; ++mt)
#pragma unroll
      for (int nt = 0; nt < 4; ++nt) acc[mt][nt] = f32x4{0.f, 0.f, 0.f, 0.f};
#pragma unroll
    for (int kk = 0; kk < 6; ++kk) {
      int kb = kk * 32 + l4 * 8;
      bf16x8 a[3], bb[4];
#pragma unroll
      for (int mt = 0; mt < 3; ++mt)
        a[mt] = frag_ld(WT + (size_t)(w * 48 + mt * 16 + l15) * 192 + kb);
#pragma unroll
      for (int nt = 0; nt < 4; ++nt)
        bb[nt] = frag_ld(sX + (nt * 16 + l15) * PX + kb);
#pragma unroll
      for (int mt = 0; mt < 3; ++mt)
#pragma unroll
        for (int nt = 0; nt < 4; ++nt)
          acc[mt][nt] = __builtin_amdgcn_mfma_f32_16x16x32_bf16(a[mt], bb[nt], acc[mt][nt], 0, 0, 0);
    }
#pragma unroll
    for (int mt = 0; mt < 3; ++mt) {
      int fb = w * 48 + mt * 16 + l4 * 4;
      float b0 = bias[fb], b1 = bias[fb + 1], b2 = bias[fb + 2], b3 = bias[fb + 3];
#pragma unroll
      for (int nt = 0; nt < 4; ++nt) {
        int n = nt * 16 + l15;
        ushort4_t u;
        u[0] = f2bf(acc[mt][nt][0] + b0);
        u[1] = f2bf(acc[mt][nt][1] + b1);
        u[2] = f2bf(acc[mt][nt][2] + b2);
        u[3] = f2bf(acc[mt][nt][3] + b3);
        *(ushort4_t*)(dst + n * PX + fb) = u;
      }
    }
  };
  conv_T(WfT, bfv, sF);
  conv_T(WgT, bgv, sG);

  // ---- conv h (forward GEMM: D[n][f] = X * Wh), store sHT[f][n] ----
  {
    f32x4 acc[4][3];
#pragma unroll
    for (int mt = 0; mt < 4; ++mt)
#pragma unroll
      for (int nt = 0; nt < 3; ++nt) acc[mt][nt] = f32x4{0.f, 0.f, 0.f, 0.f};
#pragma unroll
    for (int kk = 0; kk < 6; ++kk) {
      int kb = kk * 32 + l4 * 8;
      bf16x8 a[4], bb[3];
#pragma unroll
      for (int mt = 0; mt < 4; ++mt)
        a[mt] = frag_ld(sX + (mt * 16 + l15) * PX + kb);
#pragma unroll
      for (int nt = 0; nt < 3; ++nt)
        bb[nt] = frag_ld(WhT + (size_t)(w * 48 + nt * 16 + l15) * 192 + kb);
#pragma unroll
      for (int mt = 0; mt < 4; ++mt)
#pragma unroll
        for (int nt = 0; nt < 3; ++nt)
          acc[mt][nt] = __builtin_amdgcn_mfma_f32_16x16x32_bf16(a[mt], bb[nt], acc[mt][nt], 0, 0, 0);
    }
#pragma unroll
    for (int mt = 0; mt < 4; ++mt) {
      int nb = mt * 16 + l4 * 4;
#pragma unroll
      for (int nt = 0; nt < 3; ++nt) {
        int f = w * 48 + nt * 16 + l15;
        float bv = bhv[f];
        ushort4_t u;
#pragma unroll
        for (int j = 0; j < 4; ++j) u[j] = f2bf(acc[mt][nt][j] + bv);
        *(ushort4_t*)(sHT + f * PH + nb) = u;
      }
    }
  }
  __syncthreads();

  // ---- QK^T as logits^T = Gx * Fx^T, softmax over m (rows of logitsT) ----
  {
    f32x4 lg[4];
#pragma unroll
    for (int mt = 0; mt < 4; ++mt) lg[mt] = f32x4{0.f, 0.f, 0.f, 0.f};
#pragma unroll
    for (int kk = 0; kk < 6; ++kk) {
      int kb = kk * 32 + l4 * 8;
      bf16x8 bb = frag_ld(sF + (w * 16 + l15) * PX + kb);
#pragma unroll
      for (int mt = 0; mt < 4; ++mt) {
        bf16x8 a = frag_ld(sG + (mt * 16 + l15) * PX + kb);
        lg[mt] = __builtin_amdgcn_mfma_f32_16x16x32_bf16(a, bb, lg[mt], 0, 0, 0);
      }
    }
    // lane holds logitsT[m][n]; m = mt*16 + l4*4 + j, n = w*16 + l15 (all 16 same n)
    float mx = -1e30f;
#pragma unroll
    for (int mt = 0; mt < 4; ++mt)
#pragma unroll
      for (int j = 0; j < 4; ++j) mx = fmaxf(mx, lg[mt][j]);
    mx = fmaxf(mx, __shfl_xor(mx, 16));
    mx = fmaxf(mx, __shfl_xor(mx, 32));
    float p[4][4];
    float s = 0.f;
#pragma unroll
    for (int mt = 0; mt < 4; ++mt)
#pragma unroll
      for (int j = 0; j < 4; ++j) {
        p[mt][j] = exp2f((lg[mt][j] - mx) * 1.44269504f);
        s += p[mt][j];
      }
    s += __shfl_xor(s, 16);
    s += __shfl_xor(s, 32);
    float inv = 1.0f / s;
    int n = w * 16 + l15;
#pragma unroll
    for (int mt = 0; mt < 4; ++mt) {
      ushort4_t u;
#pragma unroll
      for (int j = 0; j < 4; ++j) u[j] = f2bf(p[mt][j] * inv);
      *(ushort4_t*)(sP + n * PP + mt * 16 + l4 * 4) = u;
    }
  }
  __syncthreads();

  // ---- PV as second^T = HxT * attn^T, store sS[n][f] (aliases sX) ----
  {
    f32x4 acc[3][4];
#pragma unroll
    for (int mt = 0; mt < 3; ++mt)
#pragma unroll
      for (int nt = 0; nt < 4; ++nt) acc[mt][nt] = f32x4{0.f, 0.f, 0.f, 0.f};
#pragma unroll
    for (int kk = 0; kk < 2; ++kk) {
      int kb = kk * 32 + l4 * 8;    // m index
      bf16x8 a[3], bb[4];
#pragma unroll
      for (int mt = 0; mt < 3; ++mt)
        a[mt] = frag_ld(sHT + (w * 48 + mt * 16 + l15) * PH + kb);
#pragma unroll
      for (int nt = 0; nt < 4; ++nt)
        bb[nt] = frag_ld(sP + (nt * 16 + l15) * PP + kb);
#pragma unroll
      for (int mt = 0; mt < 3; ++mt)
#pragma unroll
        for (int nt = 0; nt < 4; ++nt)
          acc[mt][nt] = __builtin_amdgcn_mfma_f32_16x16x32_bf16(a[mt], bb[nt], acc[mt][nt], 0, 0, 0);
    }
#pragma unroll
    for (int mt = 0; mt < 3; ++mt) {
      int fb = w * 48 + mt * 16 + l4 * 4;
#pragma unroll
      for (int nt = 0; nt < 4; ++nt) {
        int n = nt * 16 + l15;
        ushort4_t u;
#pragma unroll
        for (int j = 0; j < 4; ++j) u[j] = f2bf(acc[mt][nt][j]);
        *(ushort4_t*)(sS + n * PX + fb) = u;
      }
    }
  }
  __syncthreads();

  // ---- conv_o + bias + gamma + residual ----
  {
    f32x4 acc[4][3];
#pragma unroll
    for (int mt = 0; mt < 4; ++mt)
#pragma unroll
      for (int nt = 0; nt < 3; ++nt) acc[mt][nt] = f32x4{0.f, 0.f, 0.f, 0.f};
#pragma unroll
    for (int kk = 0; kk < 6; ++kk) {
      int kb = kk * 32 + l4 * 8;
      bf16x8 a[4], bb[3];
#pragma unroll
      for (int mt = 0; mt < 4; ++mt)
        a[mt] = frag_ld(sS + (mt * 16 + l15) * PX + kb);
#pragma unroll
      for (int nt = 0; nt < 3; ++nt)
        bb[nt] = frag_ld(WoT + (size_t)(w * 48 + nt * 16 + l15) * 192 + kb);
#pragma unroll
      for (int mt = 0; mt < 4; ++mt)
#pragma unroll
        for (int nt = 0; nt < 3; ++nt)
          acc[mt][nt] = __builtin_amdgcn_mfma_f32_16x16x32_bf16(a[mt], bb[nt], acc[mt][nt], 0, 0, 0);
    }
    float gm = gamma_p[0];
    float* ob = out + (size_t)b * (NPOS * FCH);
#pragma unroll
    for (int nt = 0; nt < 3; ++nt) {
      int d = w * 48 + nt * 16 + l15;
      float bv = bov[d];
#pragma unroll
      for (int mt = 0; mt < 4; ++mt) {
        int nb = mt * 16 + l4 * 4;
#pragma unroll
        for (int j = 0; j < 4; ++j) {
          int idx = (nb + j) * FCH + d;
          ob[idx] = xb[idx] + gm * (acc[mt][nt][j] + bv);
        }
      }
    }
  }
}

extern "C" void kernel_launch(void* const* d_in, const int* in_sizes, int n_in,
                              void* d_out, int out_size, void* d_ws, size_t ws_size,
                              hipStream_t stream) {
  const float* x   = (const float*)d_in[0];
  const float* Wf  = (const float*)d_in[1];
  const float* bf_ = (const float*)d_in[2];
  const float* Wg  = (const float*)d_in[3];
  const float* bg_ = (const float*)d_in[4];
  const float* Wh  = (const float*)d_in[5];
  const float* bh_ = (const float*)d_in[6];
  const float* Wo  = (const float*)d_in[7];
  const float* bo_ = (const float*)d_in[8];
  const float* gm  = (const float*)d_in[9];
  unsigned short* wt = (unsigned short*)d_ws;   // 4*192*192 bf16 = 294912 B

  prep_weights<<<144, 256, 0, stream>>>(Wf, Wg, Wh, Wo, wt);
  spatial_attn<<<4096, 256, 0, stream>>>(x, wt, bf_, bg_, bh_, bo_, gm, (float*)d_out);
}

// Round 2
// 476.386 us; speedup vs baseline: 1.1795x; 1.1795x over previous
//
#include <hip/hip_runtime.h>

#define FCH 192
#define NPOS 64
#define PX 200   // pitch (shorts) for [64][192]-ish buffers (400B rows: 2-way banks, free)
#define PH 72    // pitch for sH [192][64]
#define PP 72    // pitch for sP [64][64]

typedef float f32x4 __attribute__((ext_vector_type(4)));
typedef float float4_t __attribute__((ext_vector_type(4)));
typedef __bf16 bf16x8 __attribute__((ext_vector_type(8)));
typedef unsigned short ushort8_t __attribute__((ext_vector_type(8)));
typedef unsigned short ushort4_t __attribute__((ext_vector_type(4)));

__device__ __forceinline__ unsigned short f2bf(float f) {
  unsigned u = __builtin_bit_cast(unsigned, f);
  u += 0x7fffu + ((u >> 16) & 1u);   // RNE (finite inputs only)
  return (unsigned short)(u >> 16);
}
__device__ __forceinline__ float bf2f(unsigned short s) {
  unsigned u = ((unsigned)s) << 16;
  return __builtin_bit_cast(float, u);
}
__device__ __forceinline__ bf16x8 frag_ld(const unsigned short* p) {
  return __builtin_bit_cast(bf16x8, *(const ushort8_t*)p);
}

// ---- prep: AT[k'][k] = sum_f Wf[k,f]*Wg[k',f]  (bf16)
//            C2T[d][k] = sum_f Wh[k,f]*Wo[f,d]   (bf16)
__global__ void prep_mats(const float* __restrict__ Wf, const float* __restrict__ Wg,
                          const float* __restrict__ Wh, const float* __restrict__ Wo,
                          unsigned short* __restrict__ AT, unsigned short* __restrict__ C2T) {
  __shared__ float col[192];
  int r = blockIdx.x;      // 0..383
  int t = threadIdx.x;     // 0..191
  if (r < 192) {
    col[t] = Wg[r * 192 + t];
    __syncthreads();
    float acc = 0.f;
#pragma unroll 4
    for (int f = 0; f < 192; ++f) acc += Wf[t * 192 + f] * col[f];
    AT[r * 192 + t] = f2bf(acc);
  } else {
    int d = r - 192;
    col[t] = Wo[t * 192 + d];
    __syncthreads();
    float acc = 0.f;
#pragma unroll 4
    for (int f = 0; f < 192; ++f) acc += Wh[t * 192 + f] * col[f];
    C2T[d * 192 + t] = f2bf(acc);
  }
}

// ---- prep: vg[k] = sum_f Wg[k,f]*bf[f];  c0[d] = sum_f bh[f]*Wo[f,d] + bo[d]
__global__ void prep_vecs(const float* __restrict__ Wg, const float* __restrict__ bfv,
                          const float* __restrict__ Wo, const float* __restrict__ bhv,
                          const float* __restrict__ bov,
                          float* __restrict__ vg, float* __restrict__ c0) {
  int t = blockIdx.x * blockDim.x + threadIdx.x;   // 384 threads
  if (t < 192) {
    float acc = 0.f;
    for (int f = 0; f < 192; ++f) acc += Wg[t * 192 + f] * bfv[f];
    vg[t] = acc;
  } else if (t < 384) {
    int d = t - 192;
    float acc = bov[d];
    for (int f = 0; f < 192; ++f) acc += bhv[f] * Wo[f * 192 + d];
    c0[d] = acc;
  }
}

__global__ __launch_bounds__(512, 4) void spatial_attn(
    const float* __restrict__ x, const unsigned short* __restrict__ AT,
    const unsigned short* __restrict__ C2T, const float* __restrict__ vg,
    const float* __restrict__ c0, const float* __restrict__ gamma_p,
    float* __restrict__ out) {
  __shared__ unsigned short lds[31232];            // 62,464 B
  unsigned short* sX = lds;                        // [64][PX] bf16 x
  unsigned short* sY = lds + 12800;                // [64][PX] Y+vg   (region 2)
  unsigned short* sH = lds + 12800;                // [192][PH] H2^T  (aliases sY, after QK)
  unsigned short* sP = lds + 26624;                // [64][PP] attn
  unsigned short* sS = lds;                        // [64][PX] second (aliases sX, after H2)

  const int b    = blockIdx.x;
  const int tid  = threadIdx.x;
  const int lane = tid & 63;
  const int wid  = tid >> 6;      // 0..7
  const int l15  = lane & 15;
  const int l4   = lane >> 4;     // 0..3
  const int wk   = wid & 3;       // 0..3  (192-dim slice of 48)
  const int wn   = wid >> 2;      // 0..1  (64-dim slice of 32)

  const float* xb = x + (size_t)b * (NPOS * FCH);

  // ---- phase 0: stage x -> sX (bf16) ----
#pragma unroll
  for (int r = 0; r < 6; ++r) {
    int i = tid + 512 * r;                 // float4 index, 3072 total
    float4_t v = *(const float4_t*)(xb + (size_t)i * 4);
    int row = i / 48, col = (i % 48) * 4;
    ushort4_t u;
#pragma unroll
    for (int q = 0; q < 4; ++q) u[q] = f2bf(v[q]);
    *(ushort4_t*)(sX + row * PX + col) = u;
  }
  __syncthreads();

  // ---- phase 1: Y = X*A + vg  -> sY[n][k']  (transposed orientation) ----
  {
    f32x4 acc[3][2];
#pragma unroll
    for (int mt = 0; mt < 3; ++mt)
#pragma unroll
      for (int nt = 0; nt < 2; ++nt) acc[mt][nt] = f32x4{0.f, 0.f, 0.f, 0.f};
#pragma unroll
    for (int kk = 0; kk < 6; ++kk) {
      int kb = kk * 32 + l4 * 8;
      bf16x8 a[3], bb[2];
#pragma unroll
      for (int mt = 0; mt < 3; ++mt)
        a[mt] = frag_ld(AT + (size_t)(wk * 48 + mt * 16 + l15) * 192 + kb);
#pragma unroll
      for (int nt = 0; nt < 2; ++nt)
        bb[nt] = frag_ld(sX + (wn * 32 + nt * 16 + l15) * PX + kb);
#pragma unroll
      for (int mt = 0; mt < 3; ++mt)
#pragma unroll
        for (int nt = 0; nt < 2; ++nt)
          acc[mt][nt] = __builtin_amdgcn_mfma_f32_16x16x32_bf16(a[mt], bb[nt], acc[mt][nt], 0, 0, 0);
    }
#pragma unroll
    for (int mt = 0; mt < 3; ++mt) {
      int fb = wk * 48 + mt * 16 + l4 * 4;   // k'
      float b0 = vg[fb], b1 = vg[fb + 1], b2 = vg[fb + 2], b3 = vg[fb + 3];
#pragma unroll
      for (int nt = 0; nt < 2; ++nt) {
        int n = wn * 32 + nt * 16 + l15;
        ushort4_t u;
        u[0] = f2bf(acc[mt][nt][0] + b0);
        u[1] = f2bf(acc[mt][nt][1] + b1);
        u[2] = f2bf(acc[mt][nt][2] + b2);
        u[3] = f2bf(acc[mt][nt][3] + b3);
        *(ushort4_t*)(sY + n * PX + fb) = u;
      }
    }
  }
  __syncthreads();

  // ---- phase 2: logits^T[m][n] = sum_k' X[m,k']*Y[n,k'], softmax over m -> sP[n][m]
  //      (waves 0..3 only; wave = n-tile) ----
  if (wid < 4) {
    f32x4 lg[4];
#pragma unroll
    for (int mt = 0; mt < 4; ++mt) lg[mt] = f32x4{0.f, 0.f, 0.f, 0.f};
#pragma unroll
    for (int kk = 0; kk < 6; ++kk) {
      int kb = kk * 32 + l4 * 8;
      bf16x8 bb = frag_ld(sY + (wid * 16 + l15) * PX + kb);
#pragma unroll
      for (int mt = 0; mt < 4; ++mt) {
        bf16x8 a = frag_ld(sX + (mt * 16 + l15) * PX + kb);
        lg[mt] = __builtin_amdgcn_mfma_f32_16x16x32_bf16(a, bb, lg[mt], 0, 0, 0);
      }
    }
    float mx = -1e30f;
#pragma unroll
    for (int mt = 0; mt < 4; ++mt)
#pragma unroll
      for (int j = 0; j < 4; ++j) mx = fmaxf(mx, lg[mt][j]);
    mx = fmaxf(mx, __shfl_xor(mx, 16));
    mx = fmaxf(mx, __shfl_xor(mx, 32));
    float p[4][4];
    float s = 0.f;
#pragma unroll
    for (int mt = 0; mt < 4; ++mt)
#pragma unroll
      for (int j = 0; j < 4; ++j) {
        p[mt][j] = exp2f((lg[mt][j] - mx) * 1.44269504f);
        s += p[mt][j];
      }
    s += __shfl_xor(s, 16);
    s += __shfl_xor(s, 32);
    float inv = 1.0f / s;
    int n = wid * 16 + l15;
#pragma unroll
    for (int mt = 0; mt < 4; ++mt) {
      ushort4_t u;
#pragma unroll
      for (int j = 0; j < 4; ++j) u[j] = f2bf(p[mt][j] * inv);
      *(ushort4_t*)(sP + n * PP + mt * 16 + l4 * 4) = u;
    }
  }
  __syncthreads();

  // ---- phase 3: H2 = X*C2 + c0 -> sH[d'][n]  (forward orientation; overwrites sY) ----
  {
    f32x4 acc[2][3];
#pragma unroll
    for (int mt = 0; mt < 2; ++mt)
#pragma unroll
      for (int nt = 0; nt < 3; ++nt) acc[mt][nt] = f32x4{0.f, 0.f, 0.f, 0.f};
#pragma unroll
    for (int kk = 0; kk < 6; ++kk) {
      int kb = kk * 32 + l4 * 8;
      bf16x8 a[2], bb[3];
#pragma unroll
      for (int mt = 0; mt < 2; ++mt)
        a[mt] = frag_ld(sX + (wn * 32 + mt * 16 + l15) * PX + kb);
#pragma unroll
      for (int nt = 0; nt < 3; ++nt)
        bb[nt] = frag_ld(C2T + (size_t)(wk * 48 + nt * 16 + l15) * 192 + kb);
#pragma unroll
      for (int mt = 0; mt < 2; ++mt)
#pragma unroll
        for (int nt = 0; nt < 3; ++nt)
          acc[mt][nt] = __builtin_amdgcn_mfma_f32_16x16x32_bf16(a[mt], bb[nt], acc[mt][nt], 0, 0, 0);
    }
#pragma unroll
    for (int mt = 0; mt < 2; ++mt) {
      int nb = wn * 32 + mt * 16 + l4 * 4;
#pragma unroll
      for (int nt = 0; nt < 3; ++nt) {
        int d = wk * 48 + nt * 16 + l15;
        float bv = c0[d];
        ushort4_t u;
#pragma unroll
        for (int j = 0; j < 4; ++j) u[j] = f2bf(acc[mt][nt][j] + bv);
        *(ushort4_t*)(sH + d * PH + nb) = u;
      }
    }
  }
  __syncthreads();

  // ---- phase 4: second^T = H2^T * attn^T -> sS[n][d']  (overwrites sX) ----
  {
    f32x4 acc[3][2];
#pragma unroll
    for (int mt = 0; mt < 3; ++mt)
#pragma unroll
      for (int nt = 0; nt < 2; ++nt) acc[mt][nt] = f32x4{0.f, 0.f, 0.f, 0.f};
#pragma unroll
    for (int kk = 0; kk < 2; ++kk) {
      int kb = kk * 32 + l4 * 8;    // m index
      bf16x8 a[3], bb[2];
#pragma unroll
      for (int mt = 0; mt < 3; ++mt)
        a[mt] = frag_ld(sH + (wk * 48 + mt * 16 + l15) * PH + kb);
#pragma unroll
      for (int nt = 0; nt < 2; ++nt)
        bb[nt] = frag_ld(sP + (wn * 32 + nt * 16 + l15) * PP + kb);
#pragma unroll
      for (int mt = 0; mt < 3; ++mt)
#pragma unroll
        for (int nt = 0; nt < 2; ++nt)
          acc[mt][nt] = __builtin_amdgcn_mfma_f32_16x16x32_bf16(a[mt], bb[nt], acc[mt][nt], 0, 0, 0);
    }
#pragma unroll
    for (int mt = 0; mt < 3; ++mt) {
      int fb = wk * 48 + mt * 16 + l4 * 4;
#pragma unroll
      for (int nt = 0; nt < 2; ++nt) {
        int n = wn * 32 + nt * 16 + l15;
        ushort4_t u;
#pragma unroll
        for (int j = 0; j < 4; ++j) u[j] = f2bf(acc[mt][nt][j]);
        *(ushort4_t*)(sS + n * PX + fb) = u;
      }
    }
  }
  __syncthreads();

  // ---- phase 5: out = x + gamma * second  (float4 coalesced) ----
  {
    float gm = gamma_p[0];
    float* ob = out + (size_t)b * (NPOS * FCH);
#pragma unroll
    for (int r = 0; r < 6; ++r) {
      int i = tid + 512 * r;
      int row = i / 48, col = (i % 48) * 4;
      ushort4_t s4 = *(const ushort4_t*)(sS + row * PX + col);
      float4_t xv = *(const float4_t*)(xb + (size_t)i * 4);
      float4_t o;
#pragma unroll
      for (int q = 0; q < 4; ++q) o[q] = xv[q] + gm * bf2f(s4[q]);
      *(float4_t*)(ob + (size_t)i * 4) = o;
    }
  }
}

extern "C" void kernel_launch(void* const* d_in, const int* in_sizes, int n_in,
                              void* d_out, int out_size, void* d_ws, size_t ws_size,
                              hipStream_t stream) {
  const float* x   = (const float*)d_in[0];
  const float* Wf  = (const float*)d_in[1];
  const float* bf_ = (const float*)d_in[2];
  const float* Wg  = (const float*)d_in[3];
  const float* bg_ = (const float*)d_in[4];  // vanishes under softmax (per-n constant)
  const float* Wh  = (const float*)d_in[5];
  const float* bh_ = (const float*)d_in[6];
  const float* Wo  = (const float*)d_in[7];
  const float* bo_ = (const float*)d_in[8];
  const float* gm  = (const float*)d_in[9];
  (void)bg_;

  unsigned short* AT  = (unsigned short*)d_ws;                 // 36864 shorts
  unsigned short* C2T = AT + 36864;                            // 36864 shorts
  float* vg = (float*)(C2T + 36864);                           // 192 floats
  float* c0 = vg + 192;                                        // 192 floats

  prep_mats<<<384, 192, 0, stream>>>(Wf, Wg, Wh, Wo, AT, C2T);
  prep_vecs<<<2, 192, 0, stream>>>(Wg, bf_, Wo, bh_, bo_, vg, c0);
  spatial_attn<<<4096, 512, 0, stream>>>(x, AT, C2T, vg, c0, gm, (float*)d_out);
}